// Round 1
// baseline (1267.082 us; speedup 1.0000x reference)
//
#include <hip/hip_runtime.h>
#include <hip/hip_bf16.h>

#define W_WORDS 2048
#define H_DIM   1024
#define C_LAB   32
#define HID_D   512
#define MAXW    12
#define NSPAN   (W_WORDS * MAXW)

typedef __attribute__((ext_vector_type(8))) short bf16x8;
typedef __attribute__((ext_vector_type(4))) float f32x4;

__device__ __forceinline__ unsigned short f2b(float x) {
  union { float f; unsigned int i; } v; v.f = x;
  unsigned int r = v.i + 0x7FFFu + ((v.i >> 16) & 1u);
  return (unsigned short)(r >> 16);
}
__device__ __forceinline__ float b2f(unsigned short b) {
  union { float f; unsigned int i; } v; v.i = ((unsigned int)b) << 16;
  return v.f;
}

// ---------- scatter-add tokens into word buckets ----------
__global__ void scatter_k(const float* __restrict__ hs, const int* __restrict__ wm,
                          float* __restrict__ we) {
  int t = blockIdx.x;
  int m = wm[t];
  if (m <= 0) return;
  const float* src = hs + (size_t)t * H_DIM;
  float* dst = we + (size_t)(m - 1) * H_DIM;
  for (int i = threadIdx.x; i < H_DIM; i += 256)
    atomicAdd(&dst[i], src[i]);
}

// ---------- f32 -> bf16 (4 elems/thread) ----------
__global__ void cvt_k(const float* __restrict__ in, unsigned short* __restrict__ out) {
  int i = (blockIdx.x * blockDim.x + threadIdx.x) * 4;
  float4 v = *(const float4*)(in + i);
  ushort4 o = make_ushort4(f2b(v.x), f2b(v.y), f2b(v.z), f2b(v.w));
  *(ushort4*)(out + i) = o;
}

// ---------- tiled transpose: out[c][r] = in[r][c] ----------
template <int OUT_BF16>
__global__ void transpose_k(const float* __restrict__ in, void* __restrict__ outv,
                            int R, int C) {
  __shared__ float tile[32][33];
  int c0 = blockIdx.x * 32, r0 = blockIdx.y * 32;
  for (int i = threadIdx.y; i < 32; i += 8)
    tile[i][threadIdx.x] = in[(size_t)(r0 + i) * C + c0 + threadIdx.x];
  __syncthreads();
  if (OUT_BF16) {
    unsigned short* out = (unsigned short*)outv;
    for (int i = threadIdx.y; i < 32; i += 8)
      out[(size_t)(c0 + i) * R + r0 + threadIdx.x] = f2b(tile[threadIdx.x][i]);
  } else {
    float* out = (float*)outv;
    for (int i = threadIdx.y; i < 32; i += 8)
      out[(size_t)(c0 + i) * R + r0 + threadIdx.x] = tile[threadIdx.x][i];
  }
}

// ---------- small fp32 GEMM: C[m][n] = A[m]·B[:,n] + bias ----------
__global__ void sgemm_k(int N, int K, const float* __restrict__ A, int lda,
                        const float* __restrict__ B, int ldb,
                        const float* __restrict__ bias, float* __restrict__ Cc, int ldc) {
  int n = blockIdx.x * 64 + threadIdx.x;
  int m = blockIdx.y;
  if (n >= N) return;
  const float* a = A + (size_t)m * lda;
  float acc = 0.f;
  for (int k = 0; k < K; ++k)
    acc = fmaf(a[k], B[(size_t)k * ldb + n], acc);
  if (bias) acc += bias[n];
  Cc[(size_t)m * ldc + n] = acc;
}

// ---------- build K^T[(c*512+d)][h] = l1[c][h] * W1c[h][d] ----------
__global__ void kmat_k(const float* __restrict__ lab, const float* __restrict__ W1cT,
                       unsigned short* __restrict__ KT) {
  int hh = blockIdx.x * 256 + threadIdx.x;
  int row = blockIdx.y;
  int c = row >> 9, d = row & 511;
  float v = lab[(size_t)c * 2048 + 1024 + hh] * W1cT[(size_t)d * 1024 + hh];
  KT[(size_t)row * 1024 + hh] = f2b(v);
}

// ---------- bf16 MFMA GEMM, 128x128 tile, BT input (N x K) ----------
// MODE 0: outF[r*N+c] = val                        (f32 out)
// MODE 1: v=val+bias[c]; c<1024 -> out0 bf16, else out1 bf16 (tok split)
// MODE 2: h = relu(val + avec[r,d] + bvec[cc,d] + b1[d]) -> out0 bf16 (N=16384)
template <int MODE>
__global__ __launch_bounds__(256) void gemm_k(
    const unsigned short* __restrict__ A, const unsigned short* __restrict__ BT,
    int N, int K,
    float* __restrict__ outF,
    unsigned short* __restrict__ out0, unsigned short* __restrict__ out1,
    const float* __restrict__ bias,
    const float* __restrict__ avec, const float* __restrict__ bvec,
    const float* __restrict__ b1v) {
  __shared__ __align__(16) unsigned short As[128 * 32];
  __shared__ __align__(16) unsigned short Bs[128 * 32];
  int tid = threadIdx.x;
  int lane = tid & 63, wid = tid >> 6;
  int wr = wid >> 1, wc = wid & 1;
  int row0 = blockIdx.y * 128, col0 = blockIdx.x * 128;

  f32x4 zero4 = {0.f, 0.f, 0.f, 0.f};
  f32x4 acc[4][4];
#pragma unroll
  for (int i = 0; i < 4; ++i)
#pragma unroll
    for (int j = 0; j < 4; ++j) acc[i][j] = zero4;

  int sr = tid >> 2;
  int sc = (tid & 3) * 8;
  const unsigned short* gA = A + (size_t)(row0 + sr) * K + sc;
  const unsigned short* gB = BT + (size_t)(col0 + sr) * K + sc;

  int k0 = (lane >> 4) * 8;
  int fr = lane & 15;

  for (int kt = 0; kt < K; kt += 32) {
    bf16x8 a0 = *(const bf16x8*)(gA + kt);
    bf16x8 a1 = *(const bf16x8*)(gA + (size_t)64 * K + kt);
    bf16x8 b0 = *(const bf16x8*)(gB + kt);
    bf16x8 b1_ = *(const bf16x8*)(gB + (size_t)64 * K + kt);
    *(bf16x8*)&As[sr * 32 + sc] = a0;
    *(bf16x8*)&As[(sr + 64) * 32 + sc] = a1;
    *(bf16x8*)&Bs[sr * 32 + sc] = b0;
    *(bf16x8*)&Bs[(sr + 64) * 32 + sc] = b1_;
    __syncthreads();
    bf16x8 af[4], bfr[4];
#pragma unroll
    for (int i = 0; i < 4; ++i)
      af[i] = *(const bf16x8*)&As[(wr * 64 + i * 16 + fr) * 32 + k0];
#pragma unroll
    for (int i = 0; i < 4; ++i)
      bfr[i] = *(const bf16x8*)&Bs[(wc * 64 + i * 16 + fr) * 32 + k0];
#pragma unroll
    for (int mi = 0; mi < 4; ++mi)
#pragma unroll
      for (int ni = 0; ni < 4; ++ni)
        acc[mi][ni] = __builtin_amdgcn_mfma_f32_16x16x32_bf16(af[mi], bfr[ni], acc[mi][ni], 0, 0, 0);
    __syncthreads();
  }

  // C/D layout: col = lane&15, row = (lane>>4)*4 + j  [m89-verified]
  int rbase = row0 + wr * 64 + ((lane >> 4) << 2);
  int cbase = col0 + wc * 64 + fr;
#pragma unroll
  for (int mi = 0; mi < 4; ++mi) {
#pragma unroll
    for (int ni = 0; ni < 4; ++ni) {
      int ccol = cbase + ni * 16;
#pragma unroll
      for (int j = 0; j < 4; ++j) {
        int r = rbase + mi * 16 + j;
        float v = acc[mi][ni][j];
        if (MODE == 0) {
          outF[(size_t)r * N + ccol] = v;
        } else if (MODE == 1) {
          v += bias[ccol];
          if (ccol < 1024) out0[(size_t)r * 1024 + ccol] = f2b(v);
          else             out1[(size_t)r * 1024 + (ccol - 1024)] = f2b(v);
        } else {
          int cc = ccol >> 9, d = ccol & 511;
          v += avec[(size_t)r * 512 + d] + bvec[cc * 512 + d] + b1v[d];
          out0[(size_t)r * 16384 + ccol] = f2b(fmaxf(v, 0.f));
        }
      }
    }
  }
}

// ---------- scores[w,c,s] = sum_d h[w,c*512+d] * W2[d,s] + b2[s] ----------
__global__ __launch_bounds__(256) void scores_k(const unsigned short* __restrict__ h,
    const float* __restrict__ W2, const float* __restrict__ b2, float* __restrict__ outS) {
  int c = blockIdx.x, w = blockIdx.y;
  const unsigned short* hp = h + (size_t)w * 16384 + c * 512;
  float p0 = 0.f, p1 = 0.f, p2 = 0.f;
#pragma unroll
  for (int it = 0; it < 2; ++it) {
    int d = threadIdx.x + it * 256;
    float v = b2f(hp[d]);
    p0 = fmaf(v, W2[d * 3 + 0], p0);
    p1 = fmaf(v, W2[d * 3 + 1], p1);
    p2 = fmaf(v, W2[d * 3 + 2], p2);
  }
#pragma unroll
  for (int off = 32; off > 0; off >>= 1) {
    p0 += __shfl_down(p0, off);
    p1 += __shfl_down(p1, off);
    p2 += __shfl_down(p2, off);
  }
  __shared__ float r[3][4];
  int lane = threadIdx.x & 63, wv = threadIdx.x >> 6;
  if (lane == 0) { r[0][wv] = p0; r[1][wv] = p1; r[2][wv] = p2; }
  __syncthreads();
  if (threadIdx.x == 0) {
    size_t o = ((size_t)w * 32 + c) * 3;
    outS[o + 0] = r[0][0] + r[0][1] + r[0][2] + r[0][3] + b2[0];
    outS[o + 1] = r[1][0] + r[1][1] + r[1][2] + r[1][3] + b2[1];
    outS[o + 2] = r[2][0] + r[2][1] + r[2][2] + r[2][3] + b2[2];
  }
}

// ---------- is_start / is_end ----------
__global__ void mask_k(const float* __restrict__ scores, int* __restrict__ is_s,
                       int* __restrict__ is_e) {
  int w = blockIdx.x * blockDim.x + threadIdx.x;
  if (w >= W_WORDS) return;
  int s = 0, e = 0;
  for (int c = 0; c < C_LAB; ++c) {
    float a = scores[((size_t)w * 32 + c) * 3 + 0];
    float b = scores[((size_t)w * 32 + c) * 3 + 1];
    s |= (1.f / (1.f + expf(-a)) >= 0.5f);
    e |= (1.f / (1.f + expf(-b)) >= 0.5f);
  }
  is_s[w] = s;
  is_e[w] = e;
}

// ---------- span outputs ----------
__global__ __launch_bounds__(256) void span_k(const float* __restrict__ UV,
    const float* __restrict__ bsp1, const float* __restrict__ Mm,
    const float* __restrict__ cv, const int* __restrict__ is_s,
    const int* __restrict__ is_e, float* __restrict__ outIdx,
    float* __restrict__ outMask, float* __restrict__ outLog) {
  int n = blockIdx.x;
  int w = n / MAXW, j = n - w * MAXW;
  int end_raw = w + j;
  int valid = end_raw < W_WORDS;
  int end = valid ? end_raw : (W_WORDS - 1);
  int mask = valid && is_s[w] && is_e[end];
  if (threadIdx.x == 0) {
    outIdx[2 * n]     = (float)w;
    outIdx[2 * n + 1] = (float)end;
    outMask[n] = mask ? 1.0f : 0.0f;
  }
  int si = mask ? w : 0;
  int ei = mask ? end : 0;
  const float* Up = UV + (size_t)si * 2048;
  const float* Vp = UV + (size_t)ei * 2048 + 1024;
  __shared__ float rv[1024];
  for (int i = threadIdx.x; i < 1024; i += 256)
    rv[i] = fmaxf(Up[i] + Vp[i] + bsp1[i], 0.f);
  __syncthreads();
  int c = threadIdx.x & 31, g = threadIdx.x >> 5;
  float pacc = 0.f;
  int i0 = g * 128;
  for (int i = i0; i < i0 + 128; ++i)
    pacc = fmaf(rv[i], Mm[i * 32 + c], pacc);
  __shared__ float red[8][32];
  red[g][c] = pacc;
  __syncthreads();
  if (threadIdx.x < 32) {
    float s = cv[threadIdx.x];
#pragma unroll
    for (int q = 0; q < 8; ++q) s += red[q][threadIdx.x];
    outLog[(size_t)n * 32 + threadIdx.x] = s;
  }
}

extern "C" void kernel_launch(void* const* d_in, const int* in_sizes, int n_in,
                              void* d_out, int out_size, void* d_ws, size_t ws_size,
                              hipStream_t stream) {
  const float* hs   = (const float*)d_in[0];
  const int*   wm   = (const int*)d_in[1];
  const float* L    = (const float*)d_in[2];
  const float* Wt   = (const float*)d_in[3];
  const float* bt   = (const float*)d_in[4];
  const float* Wl   = (const float*)d_in[5];
  const float* bl   = (const float*)d_in[6];
  const float* W1a  = (const float*)d_in[7];
  const float* W1b  = (const float*)d_in[8];
  const float* W1c  = (const float*)d_in[9];
  const float* b1   = (const float*)d_in[10];
  const float* W2   = (const float*)d_in[11];
  const float* b2   = (const float*)d_in[12];
  const float* Wsp1 = (const float*)d_in[13];
  const float* bsp1 = (const float*)d_in[14];
  const float* Wsp2 = (const float*)d_in[15];
  const float* bsp2 = (const float*)d_in[16];

  char* p = (char*)d_ws;
  auto alloc = [&p](size_t bytes) {
    char* r = p;
    p += (bytes + 255) & ~(size_t)255;
    return r;
  };
  float*          we     = (float*)alloc((size_t)2048 * 1024 * 4);
  unsigned short* we_b   = (unsigned short*)alloc((size_t)2048 * 1024 * 2);
  unsigned short* WtT    = (unsigned short*)alloc((size_t)2048 * 1024 * 2);
  unsigned short* t0b    = (unsigned short*)alloc((size_t)2048 * 1024 * 2);
  unsigned short* t1b    = (unsigned short*)alloc((size_t)2048 * 1024 * 2);
  float*          lab    = (float*)alloc((size_t)32 * 2048 * 4);
  unsigned short* W1aT   = (unsigned short*)alloc((size_t)512 * 1024 * 2);
  float*          Avec   = (float*)alloc((size_t)2048 * 512 * 4);
  float*          Bvec   = (float*)alloc((size_t)32 * 512 * 4);
  float*          W1cT   = (float*)alloc((size_t)512 * 1024 * 4);
  unsigned short* KmatT  = (unsigned short*)alloc((size_t)16384 * 1024 * 2);
  unsigned short* hbuf   = (unsigned short*)alloc((size_t)2048 * 16384 * 2);
  int*            is_s   = (int*)alloc(2048 * 4);
  int*            is_e   = (int*)alloc(2048 * 4);
  unsigned short* Wsp1Tc = (unsigned short*)alloc((size_t)2048 * 1024 * 2);
  float*          UV     = (float*)alloc((size_t)2048 * 2048 * 4);
  float*          LT     = (float*)alloc((size_t)1024 * 32 * 4);
  float*          Mm     = (float*)alloc((size_t)1024 * 32 * 4);
  float*          cv     = (float*)alloc(32 * 4);

  float* outS    = (float*)d_out;
  float* outIdx  = outS + (size_t)2048 * 32 * 3;
  float* outMask = outIdx + (size_t)NSPAN * 2;
  float* outLog  = outMask + NSPAN;

  hipMemsetAsync(we, 0, (size_t)2048 * 1024 * 4, stream);
  scatter_k<<<3072, 256, 0, stream>>>(hs, wm, we);
  cvt_k<<<2048, 256, 0, stream>>>(we, we_b);

  transpose_k<1><<<dim3(64, 32), dim3(32, 8), 0, stream>>>(Wt, WtT, 1024, 2048);
  transpose_k<1><<<dim3(16, 32), dim3(32, 8), 0, stream>>>(W1a, W1aT, 1024, 512);
  transpose_k<1><<<dim3(32, 32), dim3(32, 8), 0, stream>>>(Wsp1, Wsp1Tc, 1024, 1024);
  transpose_k<1><<<dim3(32, 32), dim3(32, 8), 0, stream>>>(
      Wsp1 + (size_t)1024 * 1024, Wsp1Tc + (size_t)1024 * 1024, 1024, 1024);
  transpose_k<0><<<dim3(16, 32), dim3(32, 8), 0, stream>>>(W1c, W1cT, 1024, 512);
  transpose_k<0><<<dim3(32, 1), dim3(32, 8), 0, stream>>>(L, LT, 32, 1024);

  // lab = L @ Wl + bl   (32 x 2048)
  sgemm_k<<<dim3(32, 32), 64, 0, stream>>>(2048, 1024, L, 1024, Wl, 2048, bl, lab, 2048);
  // Bvec = l0 @ W1b     (32 x 512)
  sgemm_k<<<dim3(8, 32), 64, 0, stream>>>(512, 1024, lab, 2048, W1b, 512, nullptr, Bvec, 512);
  // KmatT[(c,d)][h] = l1[c][h] * W1c[h][d]
  kmat_k<<<dim3(4, 16384), 256, 0, stream>>>(lab, W1cT, KmatT);

  // tok = we @ Wt + bt -> t0b, t1b (bf16)
  gemm_k<1><<<dim3(16, 16), 256, 0, stream>>>(we_b, WtT, 2048, 1024, nullptr, t0b, t1b,
                                              bt, nullptr, nullptr, nullptr);
  // Avec = t0 @ W1a  (2048 x 512 f32)
  gemm_k<0><<<dim3(4, 16), 256, 0, stream>>>(t0b, W1aT, 512, 1024, Avec, nullptr, nullptr,
                                             nullptr, nullptr, nullptr, nullptr);
  // h = relu(t1 @ Kmat + Avec + Bvec + b1)  (2048 x 16384 bf16)
  gemm_k<2><<<dim3(128, 16), 256, 0, stream>>>(t1b, KmatT, 16384, 1024, nullptr, hbuf,
                                               nullptr, nullptr, Avec, Bvec, b1);
  // scores -> d_out
  scores_k<<<dim3(32, 2048), 256, 0, stream>>>(hbuf, W2, b2, outS);
  mask_k<<<8, 256, 0, stream>>>(outS, is_s, is_e);

  // UV = we @ [Wsp1_top | Wsp1_bot]  (2048 x 2048 f32)
  gemm_k<0><<<dim3(16, 16), 256, 0, stream>>>(we_b, Wsp1Tc, 2048, 1024, UV, nullptr,
                                              nullptr, nullptr, nullptr, nullptr, nullptr);
  // Mm = Wsp2 @ L^T (1024 x 32), cv = bsp2 @ L^T (32)
  sgemm_k<<<dim3(1, 1024), 64, 0, stream>>>(32, 1024, Wsp2, 1024, LT, 32, nullptr, Mm, 32);
  sgemm_k<<<dim3(1, 1), 64, 0, stream>>>(32, 1024, bsp2, 1024, LT, 32, nullptr, cv, 32);

  span_k<<<NSPAN, 256, 0, stream>>>(UV, bsp1, Mm, cv, is_s, is_e, outIdx, outMask, outLog);
}

// Round 2
// 508.590 us; speedup vs baseline: 2.4914x; 2.4914x over previous
//
#include <hip/hip_runtime.h>
#include <hip/hip_bf16.h>

#define W_WORDS 2048
#define H_DIM   1024
#define C_LAB   32
#define HID_D   512
#define MAXW    12
#define NSPAN   (W_WORDS * MAXW)

typedef __attribute__((ext_vector_type(8))) short bf16x8;
typedef __attribute__((ext_vector_type(4))) float f32x4;

__device__ __forceinline__ unsigned short f2b(float x) {
  union { float f; unsigned int i; } v; v.f = x;
  unsigned int r = v.i + 0x7FFFu + ((v.i >> 16) & 1u);
  return (unsigned short)(r >> 16);
}
__device__ __forceinline__ float b2f(unsigned short b) {
  union { float f; unsigned int i; } v; v.i = ((unsigned int)b) << 16;
  return v.f;
}

#define GLOAD_LDS16(g, l)                                                    \
  __builtin_amdgcn_global_load_lds(                                          \
      (const __attribute__((address_space(1))) unsigned int*)(g),            \
      (__attribute__((address_space(3))) unsigned int*)(l), 16, 0, 0)

// ---------- scatter-add tokens into word buckets ----------
__global__ void scatter_k(const float* __restrict__ hs, const int* __restrict__ wm,
                          float* __restrict__ we) {
  int t = blockIdx.x;
  int m = wm[t];
  if (m <= 0) return;
  const float* src = hs + (size_t)t * H_DIM;
  float* dst = we + (size_t)(m - 1) * H_DIM;
  for (int i = threadIdx.x; i < H_DIM; i += 256)
    atomicAdd(&dst[i], src[i]);
}

// ---------- f32 -> bf16 (4 elems/thread) ----------
__global__ void cvt_k(const float* __restrict__ in, unsigned short* __restrict__ out) {
  int i = (blockIdx.x * blockDim.x + threadIdx.x) * 4;
  float4 v = *(const float4*)(in + i);
  ushort4 o = make_ushort4(f2b(v.x), f2b(v.y), f2b(v.z), f2b(v.w));
  *(ushort4*)(out + i) = o;
}

// ---------- tiled transpose: out[c][r] = in[r][c] ----------
template <int OUT_BF16>
__global__ void transpose_k(const float* __restrict__ in, void* __restrict__ outv,
                            int R, int C) {
  __shared__ float tile[32][33];
  int c0 = blockIdx.x * 32, r0 = blockIdx.y * 32;
  for (int i = threadIdx.y; i < 32; i += 8)
    tile[i][threadIdx.x] = in[(size_t)(r0 + i) * C + c0 + threadIdx.x];
  __syncthreads();
  if (OUT_BF16) {
    unsigned short* out = (unsigned short*)outv;
    for (int i = threadIdx.y; i < 32; i += 8)
      out[(size_t)(c0 + i) * R + r0 + threadIdx.x] = f2b(tile[threadIdx.x][i]);
  } else {
    float* out = (float*)outv;
    for (int i = threadIdx.y; i < 32; i += 8)
      out[(size_t)(c0 + i) * R + r0 + threadIdx.x] = tile[threadIdx.x][i];
  }
}

// ---------- K-parallel small GEMM: out[m][n] = A[m]·B[:,n] + bias ----------
// block = 256 = 16 cols x 16 k-groups; grid = (ceil(N/16), M)
__global__ __launch_bounds__(256) void rgemm_k(int N, int K,
    const float* __restrict__ A, int lda, const float* __restrict__ B, int ldb,
    const float* __restrict__ bias, float* __restrict__ out, int ldc) {
  int m = blockIdx.y;
  int tx = threadIdx.x & 15;
  int ty = threadIdx.x >> 4;
  int n = blockIdx.x * 16 + tx;
  int kpg = K >> 4;
  float acc = 0.f;
  if (n < N) {
    const float* a = A + (size_t)m * lda + ty * kpg;
    const float* b = B + (size_t)(ty * kpg) * ldb + n;
    for (int k = 0; k < kpg; ++k)
      acc = fmaf(a[k], b[(size_t)k * ldb], acc);
  }
  __shared__ float red[16][16];
  red[ty][tx] = acc;
  __syncthreads();
  if (ty == 0 && n < N) {
    float s = 0.f;
#pragma unroll
    for (int q = 0; q < 16; ++q) s += red[q][tx];
    if (bias) s += bias[n];
    out[(size_t)m * ldc + n] = s;
  }
}

// ---------- build K^T[(c*512+d)][h] = l1[c][h] * W1c[h][d] ----------
__global__ void kmat_k(const float* __restrict__ lab, const float* __restrict__ W1cT,
                       unsigned short* __restrict__ KT) {
  int hh = blockIdx.x * 256 + threadIdx.x;
  int row = blockIdx.y;
  int c = row >> 9, d = row & 511;
  float v = lab[(size_t)c * 2048 + 1024 + hh] * W1cT[(size_t)d * 1024 + hh];
  KT[(size_t)row * 1024 + hh] = f2b(v);
}

// ---------- bf16 MFMA GEMM, 128x128 tile, BT input (N x K) ----------
// Staging via global_load_lds width=16 (m97 structure).
// MODE 0: outF[r*N+c] = val                        (f32 out)
// MODE 1: v=val+bias[c]; c<1024 -> out0 bf16, else out1 bf16 (tok split)
// MODE 2: h = relu(val + avec[r,d] + bvec[cc,d] + b1[d]) -> out0 bf16 (N=16384)
template <int MODE>
__global__ __launch_bounds__(256) void gemm_k(
    const unsigned short* __restrict__ A, const unsigned short* __restrict__ BT,
    int N, int K,
    float* __restrict__ outF,
    unsigned short* __restrict__ out0, unsigned short* __restrict__ out1,
    const float* __restrict__ bias,
    const float* __restrict__ avec, const float* __restrict__ bvec,
    const float* __restrict__ b1v) {
  __shared__ __align__(16) unsigned short As[128 * 32];
  __shared__ __align__(16) unsigned short Bs[128 * 32];
  int tid = threadIdx.x;
  int lane = tid & 63, wid = tid >> 6;
  int wr = wid >> 1, wc = wid & 1;
  int row0 = blockIdx.y * 128, col0 = blockIdx.x * 128;

  f32x4 zero4 = {0.f, 0.f, 0.f, 0.f};
  f32x4 acc[4][4];
#pragma unroll
  for (int i = 0; i < 4; ++i)
#pragma unroll
    for (int j = 0; j < 4; ++j) acc[i][j] = zero4;

  int sr = tid >> 2;
  int sc = (tid & 3) * 8;
  const unsigned short* gA = A + (size_t)(row0 + sr) * K + sc;
  const unsigned short* gB = BT + (size_t)(col0 + sr) * K + sc;
  // LDS byte offset for this thread's staged 16B = tid*16, i.e. wave-uniform
  // base (wid*512 elems) + lane*16B  -> matches global_load_lds semantics.
  unsigned short* lA0 = As + wid * 512;
  unsigned short* lA1 = As + 2048 + wid * 512;
  unsigned short* lB0 = Bs + wid * 512;
  unsigned short* lB1 = Bs + 2048 + wid * 512;

  int k0 = (lane >> 4) * 8;
  int fr = lane & 15;

  for (int kt = 0; kt < K; kt += 32) {
    GLOAD_LDS16(gA + kt, lA0);
    GLOAD_LDS16(gA + (size_t)64 * K + kt, lA1);
    GLOAD_LDS16(gB + kt, lB0);
    GLOAD_LDS16(gB + (size_t)64 * K + kt, lB1);
    __syncthreads();
    bf16x8 af[4], bfr[4];
#pragma unroll
    for (int i = 0; i < 4; ++i)
      af[i] = *(const bf16x8*)&As[(wr * 64 + i * 16 + fr) * 32 + k0];
#pragma unroll
    for (int i = 0; i < 4; ++i)
      bfr[i] = *(const bf16x8*)&Bs[(wc * 64 + i * 16 + fr) * 32 + k0];
#pragma unroll
    for (int mi = 0; mi < 4; ++mi)
#pragma unroll
      for (int ni = 0; ni < 4; ++ni)
        acc[mi][ni] = __builtin_amdgcn_mfma_f32_16x16x32_bf16(af[mi], bfr[ni], acc[mi][ni], 0, 0, 0);
    __syncthreads();
  }

  // C/D layout: col = lane&15, row = (lane>>4)*4 + j  [m89-verified]
  int rbase = row0 + wr * 64 + ((lane >> 4) << 2);
  int cbase = col0 + wc * 64 + fr;
#pragma unroll
  for (int mi = 0; mi < 4; ++mi) {
#pragma unroll
    for (int ni = 0; ni < 4; ++ni) {
      int ccol = cbase + ni * 16;
#pragma unroll
      for (int j = 0; j < 4; ++j) {
        int r = rbase + mi * 16 + j;
        float v = acc[mi][ni][j];
        if (MODE == 0) {
          outF[(size_t)r * N + ccol] = v;
        } else if (MODE == 1) {
          v += bias[ccol];
          if (ccol < 1024) out0[(size_t)r * 1024 + ccol] = f2b(v);
          else             out1[(size_t)r * 1024 + (ccol - 1024)] = f2b(v);
        } else {
          int cc = ccol >> 9, d = ccol & 511;
          v += avec[(size_t)r * 512 + d] + bvec[cc * 512 + d] + b1v[d];
          out0[(size_t)r * 16384 + ccol] = f2b(fmaxf(v, 0.f));
        }
      }
    }
  }
}

// ---------- scores[w,c,s] = sum_d h[w,c*512+d] * W2[d,s] + b2[s] ----------
__global__ __launch_bounds__(256) void scores_k(const unsigned short* __restrict__ h,
    const float* __restrict__ W2, const float* __restrict__ b2, float* __restrict__ outS) {
  int c = blockIdx.x, w = blockIdx.y;
  const unsigned short* hp = h + (size_t)w * 16384 + c * 512;
  float p0 = 0.f, p1 = 0.f, p2 = 0.f;
#pragma unroll
  for (int it = 0; it < 2; ++it) {
    int d = threadIdx.x + it * 256;
    float v = b2f(hp[d]);
    p0 = fmaf(v, W2[d * 3 + 0], p0);
    p1 = fmaf(v, W2[d * 3 + 1], p1);
    p2 = fmaf(v, W2[d * 3 + 2], p2);
  }
#pragma unroll
  for (int off = 32; off > 0; off >>= 1) {
    p0 += __shfl_down(p0, off);
    p1 += __shfl_down(p1, off);
    p2 += __shfl_down(p2, off);
  }
  __shared__ float r[3][4];
  int lane = threadIdx.x & 63, wv = threadIdx.x >> 6;
  if (lane == 0) { r[0][wv] = p0; r[1][wv] = p1; r[2][wv] = p2; }
  __syncthreads();
  if (threadIdx.x == 0) {
    size_t o = ((size_t)w * 32 + c) * 3;
    outS[o + 0] = r[0][0] + r[0][1] + r[0][2] + r[0][3] + b2[0];
    outS[o + 1] = r[1][0] + r[1][1] + r[1][2] + r[1][3] + b2[1];
    outS[o + 2] = r[2][0] + r[2][1] + r[2][2] + r[2][3] + b2[2];
  }
}

// ---------- is_start / is_end  (sigmoid(x)>=0.5 <=> x>=0) ----------
__global__ void mask_k(const float* __restrict__ scores, int* __restrict__ is_s,
                       int* __restrict__ is_e) {
  int w = blockIdx.x * blockDim.x + threadIdx.x;
  if (w >= W_WORDS) return;
  int s = 0, e = 0;
  for (int c = 0; c < C_LAB; ++c) {
    s |= (scores[((size_t)w * 32 + c) * 3 + 0] >= 0.f);
    e |= (scores[((size_t)w * 32 + c) * 3 + 1] >= 0.f);
  }
  is_s[w] = s;
  is_e[w] = e;
}

// ---------- span outputs ----------
__global__ __launch_bounds__(256) void span_k(const float* __restrict__ UV,
    const float* __restrict__ bsp1, const float* __restrict__ Mm,
    const float* __restrict__ cv, const int* __restrict__ is_s,
    const int* __restrict__ is_e, float* __restrict__ outIdx,
    float* __restrict__ outMask, float* __restrict__ outLog) {
  int n = blockIdx.x;
  int w = n / MAXW, j = n - w * MAXW;
  int end_raw = w + j;
  int valid = end_raw < W_WORDS;
  int end = valid ? end_raw : (W_WORDS - 1);
  int mask = valid && is_s[w] && is_e[end];
  if (threadIdx.x == 0) {
    outIdx[2 * n]     = (float)w;
    outIdx[2 * n + 1] = (float)end;
    outMask[n] = mask ? 1.0f : 0.0f;
  }
  int si = mask ? w : 0;
  int ei = mask ? end : 0;
  const float* Up = UV + (size_t)si * 2048;
  const float* Vp = UV + (size_t)ei * 2048 + 1024;
  __shared__ float rv[1024];
  {
    int i = threadIdx.x * 4;
    float4 u = *(const float4*)(Up + i);
    float4 vv = *(const float4*)(Vp + i);
    float4 bb = *(const float4*)(bsp1 + i);
    rv[i + 0] = fmaxf(u.x + vv.x + bb.x, 0.f);
    rv[i + 1] = fmaxf(u.y + vv.y + bb.y, 0.f);
    rv[i + 2] = fmaxf(u.z + vv.z + bb.z, 0.f);
    rv[i + 3] = fmaxf(u.w + vv.w + bb.w, 0.f);
  }
  __syncthreads();
  int c = threadIdx.x & 31, g = threadIdx.x >> 5;
  float pacc = 0.f;
  int i0 = g * 128;
  for (int i = i0; i < i0 + 128; ++i)
    pacc = fmaf(rv[i], Mm[i * 32 + c], pacc);
  __shared__ float red[8][32];
  red[g][c] = pacc;
  __syncthreads();
  if (threadIdx.x < 32) {
    float s = cv[threadIdx.x];
#pragma unroll
    for (int q = 0; q < 8; ++q) s += red[q][threadIdx.x];
    outLog[(size_t)n * 32 + threadIdx.x] = s;
  }
}

extern "C" void kernel_launch(void* const* d_in, const int* in_sizes, int n_in,
                              void* d_out, int out_size, void* d_ws, size_t ws_size,
                              hipStream_t stream) {
  const float* hs   = (const float*)d_in[0];
  const int*   wm   = (const int*)d_in[1];
  const float* L    = (const float*)d_in[2];
  const float* Wt   = (const float*)d_in[3];
  const float* bt   = (const float*)d_in[4];
  const float* Wl   = (const float*)d_in[5];
  const float* bl   = (const float*)d_in[6];
  const float* W1a  = (const float*)d_in[7];
  const float* W1b  = (const float*)d_in[8];
  const float* W1c  = (const float*)d_in[9];
  const float* b1   = (const float*)d_in[10];
  const float* W2   = (const float*)d_in[11];
  const float* b2   = (const float*)d_in[12];
  const float* Wsp1 = (const float*)d_in[13];
  const float* bsp1 = (const float*)d_in[14];
  const float* Wsp2 = (const float*)d_in[15];
  const float* bsp2 = (const float*)d_in[16];

  char* p = (char*)d_ws;
  auto alloc = [&p](size_t bytes) {
    char* r = p;
    p += (bytes + 255) & ~(size_t)255;
    return r;
  };
  float*          we     = (float*)alloc((size_t)2048 * 1024 * 4);
  unsigned short* we_b   = (unsigned short*)alloc((size_t)2048 * 1024 * 2);
  unsigned short* WtT    = (unsigned short*)alloc((size_t)2048 * 1024 * 2);
  unsigned short* t0b    = (unsigned short*)alloc((size_t)2048 * 1024 * 2);
  unsigned short* t1b    = (unsigned short*)alloc((size_t)2048 * 1024 * 2);
  float*          lab    = (float*)alloc((size_t)32 * 2048 * 4);
  unsigned short* W1aT   = (unsigned short*)alloc((size_t)512 * 1024 * 2);
  float*          Avec   = (float*)alloc((size_t)2048 * 512 * 4);
  float*          Bvec   = (float*)alloc((size_t)32 * 512 * 4);
  float*          W1cT   = (float*)alloc((size_t)512 * 1024 * 4);
  unsigned short* KmatT  = (unsigned short*)alloc((size_t)16384 * 1024 * 2);
  unsigned short* hbuf   = (unsigned short*)alloc((size_t)2048 * 16384 * 2);
  int*            is_s   = (int*)alloc(2048 * 4);
  int*            is_e   = (int*)alloc(2048 * 4);
  unsigned short* Wsp1Tc = (unsigned short*)alloc((size_t)2048 * 1024 * 2);
  float*          UV     = (float*)alloc((size_t)2048 * 2048 * 4);
  float*          LT     = (float*)alloc((size_t)1024 * 32 * 4);
  float*          Mm     = (float*)alloc((size_t)1024 * 32 * 4);
  float*          cv     = (float*)alloc(32 * 4);

  float* outS    = (float*)d_out;
  float* outIdx  = outS + (size_t)2048 * 32 * 3;
  float* outMask = outIdx + (size_t)NSPAN * 2;
  float* outLog  = outMask + NSPAN;

  hipMemsetAsync(we, 0, (size_t)2048 * 1024 * 4, stream);
  scatter_k<<<3072, 256, 0, stream>>>(hs, wm, we);
  cvt_k<<<2048, 256, 0, stream>>>(we, we_b);

  transpose_k<1><<<dim3(64, 32), dim3(32, 8), 0, stream>>>(Wt, WtT, 1024, 2048);
  transpose_k<1><<<dim3(16, 32), dim3(32, 8), 0, stream>>>(W1a, W1aT, 1024, 512);
  transpose_k<1><<<dim3(32, 32), dim3(32, 8), 0, stream>>>(Wsp1, Wsp1Tc, 1024, 1024);
  transpose_k<1><<<dim3(32, 32), dim3(32, 8), 0, stream>>>(
      Wsp1 + (size_t)1024 * 1024, Wsp1Tc + (size_t)1024 * 1024, 1024, 1024);
  transpose_k<0><<<dim3(16, 32), dim3(32, 8), 0, stream>>>(W1c, W1cT, 1024, 512);
  transpose_k<0><<<dim3(32, 1), dim3(32, 8), 0, stream>>>(L, LT, 32, 1024);

  // lab = L @ Wl + bl   (32 x 2048)
  rgemm_k<<<dim3(128, 32), 256, 0, stream>>>(2048, 1024, L, 1024, Wl, 2048, bl, lab, 2048);
  // Bvec = l0 @ W1b     (32 x 512)
  rgemm_k<<<dim3(32, 32), 256, 0, stream>>>(512, 1024, lab, 2048, W1b, 512, nullptr, Bvec, 512);
  // KmatT[(c,d)][h] = l1[c][h] * W1c[h][d]
  kmat_k<<<dim3(4, 16384), 256, 0, stream>>>(lab, W1cT, KmatT);

  // tok = we @ Wt + bt -> t0b, t1b (bf16)
  gemm_k<1><<<dim3(16, 16), 256, 0, stream>>>(we_b, WtT, 2048, 1024, nullptr, t0b, t1b,
                                              bt, nullptr, nullptr, nullptr);
  // Avec = t0 @ W1a  (2048 x 512 f32)
  gemm_k<0><<<dim3(4, 16), 256, 0, stream>>>(t0b, W1aT, 512, 1024, Avec, nullptr, nullptr,
                                             nullptr, nullptr, nullptr, nullptr);
  // h = relu(t1 @ Kmat + Avec + Bvec + b1)  (2048 x 16384 bf16)
  gemm_k<2><<<dim3(128, 16), 256, 0, stream>>>(t1b, KmatT, 16384, 1024, nullptr, hbuf,
                                               nullptr, nullptr, Avec, Bvec, b1);
  // scores -> d_out
  scores_k<<<dim3(32, 2048), 256, 0, stream>>>(hbuf, W2, b2, outS);
  mask_k<<<8, 256, 0, stream>>>(outS, is_s, is_e);

  // UV = we @ [Wsp1_top | Wsp1_bot]  (2048 x 2048 f32)
  gemm_k<0><<<dim3(16, 16), 256, 0, stream>>>(we_b, Wsp1Tc, 2048, 1024, UV, nullptr,
                                              nullptr, nullptr, nullptr, nullptr, nullptr);
  // Mm = Wsp2 @ L^T (1024 x 32), cv = bsp2 @ L^T (32)
  rgemm_k<<<dim3(2, 1024), 256, 0, stream>>>(32, 1024, Wsp2, 1024, LT, 32, nullptr, Mm, 32);
  rgemm_k<<<dim3(2, 1), 256, 0, stream>>>(32, 1024, bsp2, 1024, LT, 32, nullptr, cv, 32);

  span_k<<<NSPAN, 256, 0, stream>>>(UV, bsp1, Mm, cv, is_s, is_e, outIdx, outMask, outLog);
}

// Round 3
// 484.554 us; speedup vs baseline: 2.6149x; 1.0496x over previous
//
#include <hip/hip_runtime.h>
#include <hip/hip_bf16.h>

#define W_WORDS 2048
#define H_DIM   1024
#define C_LAB   32
#define HID_D   512
#define MAXW    12
#define NSPAN   (W_WORDS * MAXW)

typedef __attribute__((ext_vector_type(8))) short bf16x8;
typedef __attribute__((ext_vector_type(4))) float f32x4;

__device__ __forceinline__ unsigned short f2b(float x) {
  union { float f; unsigned int i; } v; v.f = x;
  unsigned int r = v.i + 0x7FFFu + ((v.i >> 16) & 1u);
  return (unsigned short)(r >> 16);
}
__device__ __forceinline__ float b2f(unsigned short b) {
  union { float f; unsigned int i; } v; v.i = ((unsigned int)b) << 16;
  return v.f;
}

#define GLOAD_LDS16(g, l)                                                    \
  __builtin_amdgcn_global_load_lds(                                          \
      (const __attribute__((address_space(1))) unsigned int*)(g),            \
      (__attribute__((address_space(3))) unsigned int*)(l), 16, 0, 0)

// ---------- scatter-add tokens into word buckets ----------
__global__ void scatter_k(const float* __restrict__ hs, const int* __restrict__ wm,
                          float* __restrict__ we) {
  int t = blockIdx.x;
  int m = wm[t];
  if (m <= 0) return;
  const float* src = hs + (size_t)t * H_DIM;
  float* dst = we + (size_t)(m - 1) * H_DIM;
  for (int i = threadIdx.x; i < H_DIM; i += 256)
    atomicAdd(&dst[i], src[i]);
}

// ---------- f32 -> bf16 (4 elems/thread; size multiple of 1024) ----------
__global__ void cvt_k(const float* __restrict__ in, unsigned short* __restrict__ out) {
  int i = (blockIdx.x * blockDim.x + threadIdx.x) * 4;
  float4 v = *(const float4*)(in + i);
  ushort4 o = make_ushort4(f2b(v.x), f2b(v.y), f2b(v.z), f2b(v.w));
  *(ushort4*)(out + i) = o;
}

// ---------- tiled transpose: out[c][r] = in[r][c] ----------
template <int OUT_BF16>
__global__ void transpose_k(const float* __restrict__ in, void* __restrict__ outv,
                            int R, int C) {
  __shared__ float tile[32][33];
  int c0 = blockIdx.x * 32, r0 = blockIdx.y * 32;
  for (int i = threadIdx.y; i < 32; i += 8)
    tile[i][threadIdx.x] = in[(size_t)(r0 + i) * C + c0 + threadIdx.x];
  __syncthreads();
  if (OUT_BF16) {
    unsigned short* out = (unsigned short*)outv;
    for (int i = threadIdx.y; i < 32; i += 8)
      out[(size_t)(c0 + i) * R + r0 + threadIdx.x] = f2b(tile[threadIdx.x][i]);
  } else {
    float* out = (float*)outv;
    for (int i = threadIdx.y; i < 32; i += 8)
      out[(size_t)(c0 + i) * R + r0 + threadIdx.x] = tile[threadIdx.x][i];
  }
}

// ---------- K-parallel small GEMM: out[m][n] = A[m]·B[:,n] + bias ----------
__global__ __launch_bounds__(256) void rgemm_k(int N, int K,
    const float* __restrict__ A, int lda, const float* __restrict__ B, int ldb,
    const float* __restrict__ bias, float* __restrict__ out, int ldc) {
  int m = blockIdx.y;
  int tx = threadIdx.x & 15;
  int ty = threadIdx.x >> 4;
  int n = blockIdx.x * 16 + tx;
  int kpg = K >> 4;
  float acc = 0.f;
  if (n < N) {
    const float* a = A + (size_t)m * lda + ty * kpg;
    const float* b = B + (size_t)(ty * kpg) * ldb + n;
    for (int k = 0; k < kpg; ++k)
      acc = fmaf(a[k], b[(size_t)k * ldb], acc);
  }
  __shared__ float red[16][16];
  red[ty][tx] = acc;
  __syncthreads();
  if (ty == 0 && n < N) {
    float s = 0.f;
#pragma unroll
    for (int q = 0; q < 16; ++q) s += red[q][tx];
    if (bias) s += bias[n];
    out[(size_t)m * ldc + n] = s;
  }
}

// ---------- build K^T[(c*512+d)][h] = l1[c][h] * W1c[h][d] ----------
__global__ void kmat_k(const float* __restrict__ lab, const float* __restrict__ W1cT,
                       unsigned short* __restrict__ KT) {
  int hh = blockIdx.x * 256 + threadIdx.x;
  int row = blockIdx.y;
  int c = row >> 9, d = row & 511;
  float v = lab[(size_t)c * 2048 + 1024 + hh] * W1cT[(size_t)d * 1024 + hh];
  KT[(size_t)row * 1024 + hh] = f2b(v);
}

// ---------- init scores to b2 ----------
__global__ void init_scores_k(const float* __restrict__ b2, float* __restrict__ outS) {
  int i = blockIdx.x * 256 + threadIdx.x;  // 196608 total
  outS[i] = b2[i % 3];
}

// ---------- bf16 MFMA GEMM, 128x128 tile, BT input (N x K) ----------
// MODE 0: outF[r*N+c] = val                         (f32 out)
// MODE 1: v=val+bias[c]; c<1024 -> out0, else out1  (tok split, bf16)
// MODE 2: fused scores: v=relu(val+avec+bvec+b1); atomicAdd(outF, v·W2)
//         (outF = scores buffer, bias = W2)
template <int MODE>
__global__ __launch_bounds__(256) void gemm_k(
    const unsigned short* __restrict__ A, const unsigned short* __restrict__ BT,
    int N, int K,
    float* __restrict__ outF,
    unsigned short* __restrict__ out0, unsigned short* __restrict__ out1,
    const float* __restrict__ bias,
    const float* __restrict__ avec, const float* __restrict__ bvec,
    const float* __restrict__ b1v) {
  __shared__ __align__(16) unsigned short As[128 * 32];
  __shared__ __align__(16) unsigned short Bs[128 * 32];
  int tid = threadIdx.x;
  int lane = tid & 63, wid = tid >> 6;
  int wr = wid >> 1, wc = wid & 1;
  int row0 = blockIdx.y * 128, col0 = blockIdx.x * 128;

  f32x4 zero4 = {0.f, 0.f, 0.f, 0.f};
  f32x4 acc[4][4];
#pragma unroll
  for (int i = 0; i < 4; ++i)
#pragma unroll
    for (int j = 0; j < 4; ++j) acc[i][j] = zero4;

  int sr = tid >> 2;
  int sc = (tid & 3) * 8;
  const unsigned short* gA = A + (size_t)(row0 + sr) * K + sc;
  const unsigned short* gB = BT + (size_t)(col0 + sr) * K + sc;
  unsigned short* lA0 = As + wid * 512;
  unsigned short* lA1 = As + 2048 + wid * 512;
  unsigned short* lB0 = Bs + wid * 512;
  unsigned short* lB1 = Bs + 2048 + wid * 512;

  int k0 = (lane >> 4) * 8;
  int fr = lane & 15;

  for (int kt = 0; kt < K; kt += 32) {
    GLOAD_LDS16(gA + kt, lA0);
    GLOAD_LDS16(gA + (size_t)64 * K + kt, lA1);
    GLOAD_LDS16(gB + kt, lB0);
    GLOAD_LDS16(gB + (size_t)64 * K + kt, lB1);
    __syncthreads();
    bf16x8 af[4], bfr[4];
#pragma unroll
    for (int i = 0; i < 4; ++i)
      af[i] = *(const bf16x8*)&As[(wr * 64 + i * 16 + fr) * 32 + k0];
#pragma unroll
    for (int i = 0; i < 4; ++i)
      bfr[i] = *(const bf16x8*)&Bs[(wc * 64 + i * 16 + fr) * 32 + k0];
#pragma unroll
    for (int mi = 0; mi < 4; ++mi)
#pragma unroll
      for (int ni = 0; ni < 4; ++ni)
        acc[mi][ni] = __builtin_amdgcn_mfma_f32_16x16x32_bf16(af[mi], bfr[ni], acc[mi][ni], 0, 0, 0);
    __syncthreads();
  }

  // C/D layout: col = lane&15, row = (lane>>4)*4 + j  [m89-verified]
  int rbase = row0 + wr * 64 + ((lane >> 4) << 2);
  int cbase = col0 + wc * 64 + fr;

  if (MODE == 2) {
    int cc = col0 >> 9;
    int dbase = (col0 & 511) + wc * 64 + fr;
#pragma unroll
    for (int mi = 0; mi < 4; ++mi) {
#pragma unroll
      for (int j = 0; j < 4; ++j) {
        int r = rbase + mi * 16 + j;
        float p0 = 0.f, p1 = 0.f, p2 = 0.f;
#pragma unroll
        for (int ni = 0; ni < 4; ++ni) {
          int d = dbase + ni * 16;
          float v = acc[mi][ni][j] + avec[(size_t)r * 512 + d] + bvec[cc * 512 + d] + b1v[d];
          v = fmaxf(v, 0.f);
          const float* w2p = bias + 3 * d;
          p0 = fmaf(v, w2p[0], p0);
          p1 = fmaf(v, w2p[1], p1);
          p2 = fmaf(v, w2p[2], p2);
        }
#pragma unroll
        for (int m = 1; m < 16; m <<= 1) {
          p0 += __shfl_xor(p0, m);
          p1 += __shfl_xor(p1, m);
          p2 += __shfl_xor(p2, m);
        }
        if ((lane & 15) == 0) {
          float* sp = outF + ((size_t)r * 32 + cc) * 3;
          atomicAdd(sp + 0, p0);
          atomicAdd(sp + 1, p1);
          atomicAdd(sp + 2, p2);
        }
      }
    }
    return;
  }

#pragma unroll
  for (int mi = 0; mi < 4; ++mi) {
#pragma unroll
    for (int ni = 0; ni < 4; ++ni) {
      int ccol = cbase + ni * 16;
#pragma unroll
      for (int j = 0; j < 4; ++j) {
        int r = rbase + mi * 16 + j;
        float v = acc[mi][ni][j];
        if (MODE == 0) {
          outF[(size_t)r * N + ccol] = v;
        } else {
          v += bias[ccol];
          if (ccol < 1024) out0[(size_t)r * 1024 + ccol] = f2b(v);
          else             out1[(size_t)r * 1024 + (ccol - 1024)] = f2b(v);
        }
      }
    }
  }
}

// ---------- is_start / is_end  (sigmoid(x)>=0.5 <=> x>=0) ----------
__global__ void mask_k(const float* __restrict__ scores, int* __restrict__ is_s,
                       int* __restrict__ is_e) {
  int w = blockIdx.x * blockDim.x + threadIdx.x;
  if (w >= W_WORDS) return;
  int s = 0, e = 0;
  for (int c = 0; c < C_LAB; ++c) {
    s |= (scores[((size_t)w * 32 + c) * 3 + 0] >= 0.f);
    e |= (scores[((size_t)w * 32 + c) * 3 + 1] >= 0.f);
  }
  is_s[w] = s;
  is_e[w] = e;
}

// ---------- R[n] = relu(U[s_n] + V[e_n] + bsp1) in bf16; also idx/mask out ----------
__global__ __launch_bounds__(256) void rbuild_k(const float* __restrict__ UV,
    const float* __restrict__ bsp1, const int* __restrict__ is_s,
    const int* __restrict__ is_e, unsigned short* __restrict__ R,
    float* __restrict__ outIdx, float* __restrict__ outMask) {
  int w = blockIdx.x;
  int i = threadIdx.x * 4;
  float4 bb = *(const float4*)(bsp1 + i);
  int s_ok = is_s[w];
#pragma unroll
  for (int j = 0; j < MAXW; ++j) {
    int n = w * MAXW + j;
    int er = w + j;
    int valid = er < W_WORDS;
    int e = valid ? er : (W_WORDS - 1);
    int mask = (valid && s_ok && is_e[e]) ? 1 : 0;
    if (threadIdx.x == 0) {
      outIdx[2 * n]     = (float)w;
      outIdx[2 * n + 1] = (float)e;
      outMask[n] = (float)mask;
    }
    int si = mask ? w : 0;
    int ei = mask ? e : 0;
    float4 u = *(const float4*)(UV + (size_t)si * 2048 + i);
    float4 v = *(const float4*)(UV + (size_t)ei * 2048 + 1024 + i);
    ushort4 o;
    o.x = f2b(fmaxf(u.x + v.x + bb.x, 0.f));
    o.y = f2b(fmaxf(u.y + v.y + bb.y, 0.f));
    o.z = f2b(fmaxf(u.z + v.z + bb.z, 0.f));
    o.w = f2b(fmaxf(u.w + v.w + bb.w, 0.f));
    *(ushort4*)(R + (size_t)n * 1024 + i) = o;
  }
}

// ---------- spanout: outLog = R @ MmT^T + cv  (24576 x 32, K=1024) ----------
__global__ __launch_bounds__(256) void spanout_k(
    const unsigned short* __restrict__ R, const unsigned short* __restrict__ MmTb,
    const float* __restrict__ cvv, float* __restrict__ outLog) {
  __shared__ __align__(16) unsigned short As[128 * 32];
  __shared__ __align__(16) unsigned short Bs[32 * 32];
  int tid = threadIdx.x;
  int lane = tid & 63, wid = tid >> 6;
  int fr = lane & 15, hi = lane >> 4;
  int k0 = hi * 8;
  int row0 = blockIdx.x * 128;

  f32x4 zero4 = {0.f, 0.f, 0.f, 0.f};
  f32x4 acc[2][2];
#pragma unroll
  for (int i = 0; i < 2; ++i)
#pragma unroll
    for (int j = 0; j < 2; ++j) acc[i][j] = zero4;

  int sr = tid >> 2;
  int sc = (tid & 3) * 8;
  const unsigned short* gA = R + (size_t)(row0 + sr) * 1024 + sc;
  const unsigned short* gB = MmTb + (size_t)sr * 1024 + sc;  // valid for tid<128
  unsigned short* lA0 = As + wid * 512;
  unsigned short* lA1 = As + 2048 + wid * 512;
  unsigned short* lB = Bs + wid * 512;

  for (int kt = 0; kt < 1024; kt += 32) {
    GLOAD_LDS16(gA + kt, lA0);
    GLOAD_LDS16(gA + (size_t)64 * 1024 + kt, lA1);
    if (tid < 128) GLOAD_LDS16(gB + kt, lB);
    __syncthreads();
    bf16x8 af[2], bfr[2];
#pragma unroll
    for (int i = 0; i < 2; ++i)
      af[i] = *(const bf16x8*)&As[(wid * 32 + i * 16 + fr) * 32 + k0];
#pragma unroll
    for (int i = 0; i < 2; ++i)
      bfr[i] = *(const bf16x8*)&Bs[(i * 16 + fr) * 32 + k0];
#pragma unroll
    for (int mi = 0; mi < 2; ++mi)
#pragma unroll
      for (int ni = 0; ni < 2; ++ni)
        acc[mi][ni] = __builtin_amdgcn_mfma_f32_16x16x32_bf16(af[mi], bfr[ni], acc[mi][ni], 0, 0, 0);
    __syncthreads();
  }

  int rbase = row0 + wid * 32 + hi * 4;
#pragma unroll
  for (int mi = 0; mi < 2; ++mi) {
#pragma unroll
    for (int ni = 0; ni < 2; ++ni) {
      int c = ni * 16 + fr;
      float cadd = cvv[c];
#pragma unroll
      for (int j = 0; j < 4; ++j) {
        int r = rbase + mi * 16 + j;
        outLog[(size_t)r * 32 + c] = acc[mi][ni][j] + cadd;
      }
    }
  }
}

extern "C" void kernel_launch(void* const* d_in, const int* in_sizes, int n_in,
                              void* d_out, int out_size, void* d_ws, size_t ws_size,
                              hipStream_t stream) {
  const float* hs   = (const float*)d_in[0];
  const int*   wm   = (const int*)d_in[1];
  const float* L    = (const float*)d_in[2];
  const float* Wt   = (const float*)d_in[3];
  const float* bt   = (const float*)d_in[4];
  const float* Wl   = (const float*)d_in[5];
  const float* bl   = (const float*)d_in[6];
  const float* W1a  = (const float*)d_in[7];
  const float* W1b  = (const float*)d_in[8];
  const float* W1c  = (const float*)d_in[9];
  const float* b1   = (const float*)d_in[10];
  const float* W2   = (const float*)d_in[11];
  const float* b2   = (const float*)d_in[12];
  const float* Wsp1 = (const float*)d_in[13];
  const float* bsp1 = (const float*)d_in[14];
  const float* Wsp2 = (const float*)d_in[15];
  const float* bsp2 = (const float*)d_in[16];

  char* p = (char*)d_ws;
  auto alloc = [&p](size_t bytes) {
    char* r = p;
    p += (bytes + 255) & ~(size_t)255;
    return r;
  };
  float*          we     = (float*)alloc((size_t)2048 * 1024 * 4);
  unsigned short* we_b   = (unsigned short*)alloc((size_t)2048 * 1024 * 2);
  unsigned short* WtT    = (unsigned short*)alloc((size_t)2048 * 1024 * 2);
  unsigned short* t0b    = (unsigned short*)alloc((size_t)2048 * 1024 * 2);
  unsigned short* t1b    = (unsigned short*)alloc((size_t)2048 * 1024 * 2);
  float*          lab    = (float*)alloc((size_t)32 * 2048 * 4);
  unsigned short* W1aT   = (unsigned short*)alloc((size_t)512 * 1024 * 2);
  float*          Avec   = (float*)alloc((size_t)2048 * 512 * 4);
  float*          Bvec   = (float*)alloc((size_t)32 * 512 * 4);
  float*          W1cT   = (float*)alloc((size_t)512 * 1024 * 4);
  unsigned short* KmatT  = (unsigned short*)alloc((size_t)16384 * 1024 * 2);
  int*            is_s   = (int*)alloc(2048 * 4);
  int*            is_e   = (int*)alloc(2048 * 4);
  unsigned short* Wsp1Tc = (unsigned short*)alloc((size_t)2048 * 1024 * 2);
  float*          UV     = (float*)alloc((size_t)2048 * 2048 * 4);
  float*          LT     = (float*)alloc((size_t)1024 * 32 * 4);
  float*          Wsp2T  = (float*)alloc((size_t)1024 * 1024 * 4);
  float*          MmTf   = (float*)alloc((size_t)32 * 1024 * 4);
  unsigned short* MmTb   = (unsigned short*)alloc((size_t)32 * 1024 * 2);
  float*          cv     = (float*)alloc(32 * 4);
  unsigned short* R      = (unsigned short*)alloc((size_t)NSPAN * 1024 * 2);

  float* outS    = (float*)d_out;
  float* outIdx  = outS + (size_t)2048 * 32 * 3;
  float* outMask = outIdx + (size_t)NSPAN * 2;
  float* outLog  = outMask + NSPAN;

  hipMemsetAsync(we, 0, (size_t)2048 * 1024 * 4, stream);
  scatter_k<<<3072, 256, 0, stream>>>(hs, wm, we);
  cvt_k<<<2048, 256, 0, stream>>>(we, we_b);

  transpose_k<1><<<dim3(64, 32), dim3(32, 8), 0, stream>>>(Wt, WtT, 1024, 2048);
  transpose_k<1><<<dim3(16, 32), dim3(32, 8), 0, stream>>>(W1a, W1aT, 1024, 512);
  transpose_k<1><<<dim3(32, 32), dim3(32, 8), 0, stream>>>(Wsp1, Wsp1Tc, 1024, 1024);
  transpose_k<1><<<dim3(32, 32), dim3(32, 8), 0, stream>>>(
      Wsp1 + (size_t)1024 * 1024, Wsp1Tc + (size_t)1024 * 1024, 1024, 1024);
  transpose_k<0><<<dim3(16, 32), dim3(32, 8), 0, stream>>>(W1c, W1cT, 1024, 512);
  transpose_k<0><<<dim3(32, 1), dim3(32, 8), 0, stream>>>(L, LT, 32, 1024);
  transpose_k<0><<<dim3(32, 32), dim3(32, 8), 0, stream>>>(Wsp2, Wsp2T, 1024, 1024);

  // lab = L @ Wl + bl   (32 x 2048)
  rgemm_k<<<dim3(128, 32), 256, 0, stream>>>(2048, 1024, L, 1024, Wl, 2048, bl, lab, 2048);
  // Bvec = l0 @ W1b     (32 x 512)
  rgemm_k<<<dim3(32, 32), 256, 0, stream>>>(512, 1024, lab, 2048, W1b, 512, nullptr, Bvec, 512);
  // MmT[n][k] = sum_h L[n][h] Wsp2T[h][k]   (32 x 1024)
  rgemm_k<<<dim3(64, 32), 256, 0, stream>>>(1024, 1024, L, 1024, Wsp2T, 1024, nullptr, MmTf, 1024);
  // cv = bsp2 @ L^T  (32)
  rgemm_k<<<dim3(2, 1), 256, 0, stream>>>(32, 1024, bsp2, 1024, LT, 32, nullptr, cv, 32);
  cvt_k<<<32, 256, 0, stream>>>(MmTf, MmTb);

  // KmatT[(c,d)][h] = l1[c][h] * W1c[h][d]
  kmat_k<<<dim3(4, 16384), 256, 0, stream>>>(lab, W1cT, KmatT);

  // tok = we @ Wt + bt -> t0b, t1b (bf16)
  gemm_k<1><<<dim3(16, 16), 256, 0, stream>>>(we_b, WtT, 2048, 1024, nullptr, t0b, t1b,
                                              bt, nullptr, nullptr, nullptr);
  // Avec = t0 @ W1a  (2048 x 512 f32)
  gemm_k<0><<<dim3(4, 16), 256, 0, stream>>>(t0b, W1aT, 512, 1024, Avec, nullptr, nullptr,
                                             nullptr, nullptr, nullptr, nullptr);

  // scores = b2; += per-tile contributions of relu(t1@Kmat + Avec + Bvec + b1) @ W2
  init_scores_k<<<768, 256, 0, stream>>>(b2, outS);
  gemm_k<2><<<dim3(128, 16), 256, 0, stream>>>(t1b, KmatT, 16384, 1024, outS, nullptr,
                                               nullptr, W2, Avec, Bvec, b1);
  mask_k<<<8, 256, 0, stream>>>(outS, is_s, is_e);

  // UV = we @ [Wsp1_top | Wsp1_bot]  (2048 x 2048 f32)
  gemm_k<0><<<dim3(16, 16), 256, 0, stream>>>(we_b, Wsp1Tc, 2048, 1024, UV, nullptr,
                                              nullptr, nullptr, nullptr, nullptr, nullptr);

  // R = relu(U[s]+V[e]+bsp1) bf16; span idx/mask outputs
  rbuild_k<<<2048, 256, 0, stream>>>(UV, bsp1, is_s, is_e, R, outIdx, outMask);
  // span_logits = R @ MmT^T + cv
  spanout_k<<<192, 256, 0, stream>>>(R, MmTb, cv, outLog);
}

// Round 4
// 378.334 us; speedup vs baseline: 3.3491x; 1.2808x over previous
//
#include <hip/hip_runtime.h>
#include <hip/hip_bf16.h>

#define W_WORDS 2048
#define H_DIM   1024
#define C_LAB   32
#define HID_D   512
#define MAXW    12
#define NSPAN   (W_WORDS * MAXW)

typedef __attribute__((ext_vector_type(8))) short bf16x8;
typedef __attribute__((ext_vector_type(4))) float f32x4;

__device__ __forceinline__ unsigned short f2b(float x) {
  union { float f; unsigned int i; } v; v.f = x;
  unsigned int r = v.i + 0x7FFFu + ((v.i >> 16) & 1u);
  return (unsigned short)(r >> 16);
}
__device__ __forceinline__ float b2f(unsigned short b) {
  union { float f; unsigned int i; } v; v.i = ((unsigned int)b) << 16;
  return v.f;
}

#define GLOAD_LDS16(g, l)                                                    \
  __builtin_amdgcn_global_load_lds(                                          \
      (const __attribute__((address_space(1))) unsigned int*)(g),            \
      (__attribute__((address_space(3))) unsigned int*)(l), 16, 0, 0)

// ---------- scatter-add tokens into word buckets ----------
__global__ void scatter_k(const float* __restrict__ hs, const int* __restrict__ wm,
                          float* __restrict__ we) {
  int t = blockIdx.x;
  int m = wm[t];
  if (m <= 0) return;
  const float* src = hs + (size_t)t * H_DIM;
  float* dst = we + (size_t)(m - 1) * H_DIM;
  for (int i = threadIdx.x; i < H_DIM; i += 256)
    atomicAdd(&dst[i], src[i]);
}

// ---------- f32 -> bf16 (4 elems/thread; size multiple of 1024) ----------
__global__ void cvt_k(const float* __restrict__ in, unsigned short* __restrict__ out) {
  int i = (blockIdx.x * blockDim.x + threadIdx.x) * 4;
  float4 v = *(const float4*)(in + i);
  ushort4 o = make_ushort4(f2b(v.x), f2b(v.y), f2b(v.z), f2b(v.w));
  *(ushort4*)(out + i) = o;
}

// ---------- all weight transposes in one launch (blockIdx.z selects) ----------
__global__ void transpose_all_k(
    const float* __restrict__ Wt, const float* __restrict__ W1a,
    const float* __restrict__ Wsp1, const float* __restrict__ W1c,
    const float* __restrict__ L, const float* __restrict__ Wsp2,
    unsigned short* __restrict__ WtT, unsigned short* __restrict__ W1aT,
    unsigned short* __restrict__ Wsp1Tc, float* __restrict__ W1cT,
    float* __restrict__ LT, float* __restrict__ Wsp2T) {
  const float* in;
  void* out;
  int R, C, obf;
  switch (blockIdx.z) {
    case 0: in = Wt;   out = WtT;    R = 1024; C = 2048; obf = 1; break;
    case 1: in = W1a;  out = W1aT;   R = 1024; C = 512;  obf = 1; break;
    case 2: in = Wsp1; out = Wsp1Tc; R = 1024; C = 1024; obf = 1; break;
    case 3: in = Wsp1 + 1048576; out = Wsp1Tc + 1048576; R = 1024; C = 1024; obf = 1; break;
    case 4: in = W1c;  out = W1cT;   R = 1024; C = 512;  obf = 0; break;
    case 5: in = L;    out = LT;     R = 32;   C = 1024; obf = 0; break;
    default: in = Wsp2; out = Wsp2T; R = 1024; C = 1024; obf = 0; break;
  }
  int c0 = blockIdx.x * 32, r0 = blockIdx.y * 32;
  if (c0 >= C || r0 >= R) return;
  __shared__ float tile[32][33];
  for (int i = threadIdx.y; i < 32; i += 8)
    tile[i][threadIdx.x] = in[(size_t)(r0 + i) * C + c0 + threadIdx.x];
  __syncthreads();
  if (obf) {
    unsigned short* o = (unsigned short*)out;
    for (int i = threadIdx.y; i < 32; i += 8)
      o[(size_t)(c0 + i) * R + r0 + threadIdx.x] = f2b(tile[threadIdx.x][i]);
  } else {
    float* o = (float*)out;
    for (int i = threadIdx.y; i < 32; i += 8)
      o[(size_t)(c0 + i) * R + r0 + threadIdx.x] = tile[threadIdx.x][i];
  }
}

// ---------- K-parallel small GEMM: out[m][n] = A[m]·B[:,n] + bias ----------
__global__ __launch_bounds__(256) void rgemm_k(int N, int K,
    const float* __restrict__ A, int lda, const float* __restrict__ B, int ldb,
    const float* __restrict__ bias, float* __restrict__ out, int ldc) {
  int m = blockIdx.y;
  int tx = threadIdx.x & 15;
  int ty = threadIdx.x >> 4;
  int n = blockIdx.x * 16 + tx;
  int kpg = K >> 4;
  float acc = 0.f;
  if (n < N) {
    const float* a = A + (size_t)m * lda + ty * kpg;
    const float* b = B + (size_t)(ty * kpg) * ldb + n;
    for (int k = 0; k < kpg; ++k)
      acc = fmaf(a[k], b[(size_t)k * ldb], acc);
  }
  __shared__ float red[16][16];
  red[ty][tx] = acc;
  __syncthreads();
  if (ty == 0 && n < N) {
    float s = 0.f;
#pragma unroll
    for (int q = 0; q < 16; ++q) s += red[q][tx];
    if (bias) s += bias[n];
    out[(size_t)m * ldc + n] = s;
  }
}

// ---------- build K^T[(c*512+d)][h] = l1[c][h] * W1c[h][d] ----------
__global__ void kmat_k(const float* __restrict__ lab, const float* __restrict__ W1cT,
                       unsigned short* __restrict__ KT) {
  int hh = blockIdx.x * 256 + threadIdx.x;
  int row = blockIdx.y;
  int c = row >> 9, d = row & 511;
  float v = lab[(size_t)c * 2048 + 1024 + hh] * W1cT[(size_t)d * 1024 + hh];
  KT[(size_t)row * 1024 + hh] = f2b(v);
}

// ---------- W2padT[n][d] = n<3 ? W2[d][n] : 0   (16 x 512 bf16) ----------
__global__ void w2padt_k(const float* __restrict__ W2, unsigned short* __restrict__ o) {
  int i = blockIdx.x * 256 + threadIdx.x;  // 8192
  int n = i >> 9, d = i & 511;
  o[i] = f2b(n < 3 ? W2[d * 3 + n] : 0.f);
}

// ---------- bf16 MFMA GEMM, 128x128 tile, BT input (rows x K) ----------
// MODE 0: outF[r*N+c] = val                               (f32)
// MODE 1: c<2048: v+=bias -> out0/out1 bf16 (tok); else outF (UV f32, ld 2048)
// MODE 2: h=relu(val+avec+bvec) -> LDS bf16 -> MFMA vs w2t -> scoresPart slice
template <int MODE>
__global__ __launch_bounds__(256) void gemm_k(
    const unsigned short* __restrict__ A, const unsigned short* __restrict__ BT,
    int N, int K,
    float* __restrict__ outF,
    unsigned short* __restrict__ out0, unsigned short* __restrict__ out1,
    const float* __restrict__ bias,
    const float* __restrict__ avec, const float* __restrict__ bvec,
    const unsigned short* __restrict__ w2t) {
  extern __shared__ __align__(16) unsigned short smem[];
  unsigned short* As = smem;
  unsigned short* Bs = smem + 4096;
  int tid = threadIdx.x;
  int lane = tid & 63, wid = tid >> 6;
  int wr = wid >> 1, wc = wid & 1;
  int row0 = blockIdx.y * 128, col0 = blockIdx.x * 128;

  f32x4 zero4 = {0.f, 0.f, 0.f, 0.f};
  f32x4 acc[4][4];
#pragma unroll
  for (int i = 0; i < 4; ++i)
#pragma unroll
    for (int j = 0; j < 4; ++j) acc[i][j] = zero4;

  int sr = tid >> 2;
  int sc = (tid & 3) * 8;
  const unsigned short* gA = A + (size_t)(row0 + sr) * K + sc;
  const unsigned short* gB = BT + (size_t)(col0 + sr) * K + sc;
  unsigned short* lA0 = As + wid * 512;
  unsigned short* lA1 = As + 2048 + wid * 512;
  unsigned short* lB0 = Bs + wid * 512;
  unsigned short* lB1 = Bs + 2048 + wid * 512;

  int hi = lane >> 4;
  int fr = lane & 15;
  int k0 = hi * 8;

  for (int kt = 0; kt < K; kt += 32) {
    GLOAD_LDS16(gA + kt, lA0);
    GLOAD_LDS16(gA + (size_t)64 * K + kt, lA1);
    GLOAD_LDS16(gB + kt, lB0);
    GLOAD_LDS16(gB + (size_t)64 * K + kt, lB1);
    __syncthreads();
    bf16x8 af[4], bfr[4];
#pragma unroll
    for (int i = 0; i < 4; ++i)
      af[i] = *(const bf16x8*)&As[(wr * 64 + i * 16 + fr) * 32 + k0];
#pragma unroll
    for (int i = 0; i < 4; ++i)
      bfr[i] = *(const bf16x8*)&Bs[(wc * 64 + i * 16 + fr) * 32 + k0];
#pragma unroll
    for (int mi = 0; mi < 4; ++mi)
#pragma unroll
      for (int ni = 0; ni < 4; ++ni)
        acc[mi][ni] = __builtin_amdgcn_mfma_f32_16x16x32_bf16(af[mi], bfr[ni], acc[mi][ni], 0, 0, 0);
    __syncthreads();
  }

  // C/D layout: col = lane&15, row = (lane>>4)*4 + j  [m89-verified]
  if (MODE == 2) {
    int cc = col0 >> 9;
    int dg0 = col0 & 511;
    // h tile -> swizzled LDS (reuses staging smem; 32 KB)
#pragma unroll
    for (int mi = 0; mi < 4; ++mi) {
#pragma unroll
      for (int j = 0; j < 4; ++j) {
        int rl = wr * 64 + hi * 4 + mi * 16 + j;
        const float* avp = avec + (size_t)(row0 + rl) * 512 + dg0;
        const float* bvp = bvec + (size_t)cc * 512 + dg0;
#pragma unroll
        for (int ni = 0; ni < 4; ++ni) {
          int cl = wc * 64 + ni * 16 + fr;
          float v = acc[mi][ni][j] + avp[cl] + bvp[cl];
          v = fmaxf(v, 0.f);
          int slot = cl >> 3;
          smem[rl * 128 + (((slot ^ rl) & 7) << 3) + (slot & 8) * 8 + (cl & 7)] = f2b(v);
        }
      }
    }
    __syncthreads();
    // scores tile: [128 x 3] = h[128 x 128] @ W2padT^T[128 x 16(3)]
    f32x4 s0 = zero4, s1 = zero4;
    int r0l = wid * 32 + fr;
    int r1l = wid * 32 + 16 + fr;
#pragma unroll
    for (int kt2 = 0; kt2 < 4; ++kt2) {
      int slot = kt2 * 4 + hi;
      bf16x8 a0 = *(const bf16x8*)&smem[r0l * 128 + (((slot ^ r0l) & 7) << 3) + (slot & 8) * 8];
      bf16x8 a1 = *(const bf16x8*)&smem[r1l * 128 + (((slot ^ r1l) & 7) << 3) + (slot & 8) * 8];
      bf16x8 b = *(const bf16x8*)&w2t[(size_t)fr * 512 + dg0 + kt2 * 32 + hi * 8];
      s0 = __builtin_amdgcn_mfma_f32_16x16x32_bf16(a0, b, s0, 0, 0, 0);
      s1 = __builtin_amdgcn_mfma_f32_16x16x32_bf16(a1, b, s1, 0, 0, 0);
    }
    if (fr < 3) {
      size_t base = ((size_t)(blockIdx.x & 3) * 2048 + row0) * 96 + cc * 3 + fr;
#pragma unroll
      for (int j = 0; j < 4; ++j) {
        outF[base + (size_t)(wid * 32 + hi * 4 + j) * 96] = s0[j];
        outF[base + (size_t)(wid * 32 + 16 + hi * 4 + j) * 96] = s1[j];
      }
    }
    return;
  }

  int rbase = row0 + wr * 64 + (hi << 2);
  int cbase = col0 + wc * 64 + fr;
#pragma unroll
  for (int mi = 0; mi < 4; ++mi) {
#pragma unroll
    for (int ni = 0; ni < 4; ++ni) {
      int ccol = cbase + ni * 16;
#pragma unroll
      for (int j = 0; j < 4; ++j) {
        int r = rbase + mi * 16 + j;
        float v = acc[mi][ni][j];
        if (MODE == 0) {
          outF[(size_t)r * N + ccol] = v;
        } else {
          if (ccol < 2048) {
            v += bias[ccol];
            if (ccol < 1024) out0[(size_t)r * 1024 + ccol] = f2b(v);
            else             out1[(size_t)r * 1024 + (ccol - 1024)] = f2b(v);
          } else {
            outF[(size_t)r * 2048 + (ccol - 2048)] = v;
          }
        }
      }
    }
  }
}

// ---------- fold 4 score slices + b2 ----------
__global__ void foldscores_k(const float* __restrict__ part, const float* __restrict__ b2,
                             float* __restrict__ outS) {
  int i = blockIdx.x * 256 + threadIdx.x;  // 196608
  float s = b2[i % 3];
  s += part[i] + part[196608 + i] + part[2 * 196608 + i] + part[3 * 196608 + i];
  outS[i] = s;
}

// ---------- is_start / is_end  (sigmoid(x)>=0.5 <=> x>=0) ----------
__global__ void mask_k(const float* __restrict__ scores, int* __restrict__ is_s,
                       int* __restrict__ is_e) {
  int w = blockIdx.x * blockDim.x + threadIdx.x;
  if (w >= W_WORDS) return;
  int s = 0, e = 0;
  for (int c = 0; c < C_LAB; ++c) {
    s |= (scores[((size_t)w * 32 + c) * 3 + 0] >= 0.f);
    e |= (scores[((size_t)w * 32 + c) * 3 + 1] >= 0.f);
  }
  is_s[w] = s;
  is_e[w] = e;
}

// ---------- R[n] = relu(U[s_n] + V[e_n] + bsp1) bf16; idx/mask out ----------
__global__ __launch_bounds__(256) void rbuild_k(const float* __restrict__ UV,
    const float* __restrict__ bsp1, const int* __restrict__ is_s,
    const int* __restrict__ is_e, unsigned short* __restrict__ R,
    float* __restrict__ outIdx, float* __restrict__ outMask) {
  int w = blockIdx.x;
  int i = threadIdx.x * 4;
  float4 bb = *(const float4*)(bsp1 + i);
  int s_ok = is_s[w];
#pragma unroll
  for (int j = 0; j < MAXW; ++j) {
    int n = w * MAXW + j;
    int er = w + j;
    int valid = er < W_WORDS;
    int e = valid ? er : (W_WORDS - 1);
    int mask = (valid && s_ok && is_e[e]) ? 1 : 0;
    if (threadIdx.x == 0) {
      outIdx[2 * n]     = (float)w;
      outIdx[2 * n + 1] = (float)e;
      outMask[n] = (float)mask;
    }
    int si = mask ? w : 0;
    int ei = mask ? e : 0;
    float4 u = *(const float4*)(UV + (size_t)si * 2048 + i);
    float4 v = *(const float4*)(UV + (size_t)ei * 2048 + 1024 + i);
    ushort4 o;
    o.x = f2b(fmaxf(u.x + v.x + bb.x, 0.f));
    o.y = f2b(fmaxf(u.y + v.y + bb.y, 0.f));
    o.z = f2b(fmaxf(u.z + v.z + bb.z, 0.f));
    o.w = f2b(fmaxf(u.w + v.w + bb.w, 0.f));
    *(ushort4*)(R + (size_t)n * 1024 + i) = o;
  }
}

// ---------- spanout: outLog = R @ MmT^T + cv  (24576 x 32, K=1024) ----------
__global__ __launch_bounds__(256) void spanout_k(
    const unsigned short* __restrict__ R, const unsigned short* __restrict__ MmTb,
    const float* __restrict__ cvv, float* __restrict__ outLog) {
  __shared__ __align__(16) unsigned short As2[128 * 32];
  __shared__ __align__(16) unsigned short Bs2[32 * 32];
  int tid = threadIdx.x;
  int lane = tid & 63, wid = tid >> 6;
  int fr = lane & 15, hi = lane >> 4;
  int k0 = hi * 8;
  int row0 = blockIdx.x * 128;

  f32x4 zero4 = {0.f, 0.f, 0.f, 0.f};
  f32x4 acc[2][2];
#pragma unroll
  for (int i = 0; i < 2; ++i)
#pragma unroll
    for (int j = 0; j < 2; ++j) acc[i][j] = zero4;

  int sr = tid >> 2;
  int sc = (tid & 3) * 8;
  const unsigned short* gA = R + (size_t)(row0 + sr) * 1024 + sc;
  const unsigned short* gB = MmTb + (size_t)sr * 1024 + sc;
  unsigned short* lA0 = As2 + wid * 512;
  unsigned short* lA1 = As2 + 2048 + wid * 512;
  unsigned short* lB = Bs2 + wid * 512;

  for (int kt = 0; kt < 1024; kt += 32) {
    GLOAD_LDS16(gA + kt, lA0);
    GLOAD_LDS16(gA + (size_t)64 * 1024 + kt, lA1);
    if (tid < 128) GLOAD_LDS16(gB + kt, lB);
    __syncthreads();
    bf16x8 af[2], bfr[2];
#pragma unroll
    for (int i = 0; i < 2; ++i)
      af[i] = *(const bf16x8*)&As2[(wid * 32 + i * 16 + fr) * 32 + k0];
#pragma unroll
    for (int i = 0; i < 2; ++i)
      bfr[i] = *(const bf16x8*)&Bs2[(i * 16 + fr) * 32 + k0];
#pragma unroll
    for (int mi = 0; mi < 2; ++mi)
#pragma unroll
      for (int ni = 0; ni < 2; ++ni)
        acc[mi][ni] = __builtin_amdgcn_mfma_f32_16x16x32_bf16(af[mi], bfr[ni], acc[mi][ni], 0, 0, 0);
    __syncthreads();
  }

  int rbase = row0 + wid * 32 + hi * 4;
#pragma unroll
  for (int mi = 0; mi < 2; ++mi) {
#pragma unroll
    for (int ni = 0; ni < 2; ++ni) {
      int c = ni * 16 + fr;
      float cadd = cvv[c];
#pragma unroll
      for (int j = 0; j < 4; ++j) {
        int r = rbase + mi * 16 + j;
        outLog[(size_t)r * 32 + c] = acc[mi][ni][j] + cadd;
      }
    }
  }
}

extern "C" void kernel_launch(void* const* d_in, const int* in_sizes, int n_in,
                              void* d_out, int out_size, void* d_ws, size_t ws_size,
                              hipStream_t stream) {
  const float* hs   = (const float*)d_in[0];
  const int*   wm   = (const int*)d_in[1];
  const float* L    = (const float*)d_in[2];
  const float* Wt   = (const float*)d_in[3];
  const float* bt   = (const float*)d_in[4];
  const float* Wl   = (const float*)d_in[5];
  const float* bl   = (const float*)d_in[6];
  const float* W1a  = (const float*)d_in[7];
  const float* W1b  = (const float*)d_in[8];
  const float* W1c  = (const float*)d_in[9];
  const float* b1   = (const float*)d_in[10];
  const float* W2   = (const float*)d_in[11];
  const float* b2   = (const float*)d_in[12];
  const float* Wsp1 = (const float*)d_in[13];
  const float* bsp1 = (const float*)d_in[14];
  const float* Wsp2 = (const float*)d_in[15];
  const float* bsp2 = (const float*)d_in[16];

  char* p = (char*)d_ws;
  auto alloc = [&p](size_t bytes) {
    char* r = p;
    p += (bytes + 255) & ~(size_t)255;
    return r;
  };
  float*          we     = (float*)alloc((size_t)2048 * 1024 * 4);
  unsigned short* we_b   = (unsigned short*)alloc((size_t)2048 * 1024 * 2);
  // WtT and Wsp1Tc MUST be adjacent: merged BT = [WtT ; Wsp1Tc] (4096 x 1024)
  unsigned short* WtT    = (unsigned short*)alloc((size_t)2048 * 1024 * 2);
  unsigned short* Wsp1Tc = (unsigned short*)alloc((size_t)2048 * 1024 * 2);
  unsigned short* t0b    = (unsigned short*)alloc((size_t)2048 * 1024 * 2);
  unsigned short* t1b    = (unsigned short*)alloc((size_t)2048 * 1024 * 2);
  float*          lab    = (float*)alloc((size_t)32 * 2048 * 4);
  unsigned short* W1aT   = (unsigned short*)alloc((size_t)512 * 1024 * 2);
  float*          Avec   = (float*)alloc((size_t)2048 * 512 * 4);
  float*          BvecB  = (float*)alloc((size_t)32 * 512 * 4);
  float*          W1cT   = (float*)alloc((size_t)512 * 1024 * 4);
  unsigned short* KmatT  = (unsigned short*)alloc((size_t)16384 * 1024 * 2);
  float*          sPart  = (float*)alloc((size_t)4 * 2048 * 96 * 4);
  int*            is_s   = (int*)alloc(2048 * 4);
  int*            is_e   = (int*)alloc(2048 * 4);
  float*          UV     = (float*)alloc((size_t)2048 * 2048 * 4);
  float*          LT     = (float*)alloc((size_t)1024 * 32 * 4);
  float*          Wsp2T  = (float*)alloc((size_t)1024 * 1024 * 4);
  float*          MmTf   = (float*)alloc((size_t)32 * 1024 * 4);
  unsigned short* MmTb   = (unsigned short*)alloc((size_t)32 * 1024 * 2);
  float*          cv     = (float*)alloc(32 * 4);
  unsigned short* W2padT = (unsigned short*)alloc((size_t)16 * 512 * 2);
  unsigned short* R      = (unsigned short*)alloc((size_t)NSPAN * 1024 * 2);

  float* outS    = (float*)d_out;
  float* outIdx  = outS + (size_t)2048 * 32 * 3;
  float* outMask = outIdx + (size_t)NSPAN * 2;
  float* outLog  = outMask + NSPAN;

  hipMemsetAsync(we, 0, (size_t)2048 * 1024 * 4, stream);
  scatter_k<<<3072, 256, 0, stream>>>(hs, wm, we);
  cvt_k<<<2048, 256, 0, stream>>>(we, we_b);

  transpose_all_k<<<dim3(64, 32, 7), dim3(32, 8), 0, stream>>>(
      Wt, W1a, Wsp1, W1c, L, Wsp2, WtT, W1aT, Wsp1Tc, W1cT, LT, Wsp2T);

  // lab = L @ Wl + bl   (32 x 2048)
  rgemm_k<<<dim3(128, 32), 256, 0, stream>>>(2048, 1024, L, 1024, Wl, 2048, bl, lab, 2048);
  // BvecB = l0 @ W1b + b1   (32 x 512)
  rgemm_k<<<dim3(32, 32), 256, 0, stream>>>(512, 1024, lab, 2048, W1b, 512, b1, BvecB, 512);
  // MmT[n][k] = sum_h L[n][h] Wsp2T[h][k]   (32 x 1024)
  rgemm_k<<<dim3(64, 32), 256, 0, stream>>>(1024, 1024, L, 1024, Wsp2T, 1024, nullptr, MmTf, 1024);
  // cv = bsp2 @ L^T  (32)
  rgemm_k<<<dim3(2, 1), 256, 0, stream>>>(32, 1024, bsp2, 1024, LT, 32, nullptr, cv, 32);
  cvt_k<<<32, 256, 0, stream>>>(MmTf, MmTb);
  w2padt_k<<<32, 256, 0, stream>>>(W2, W2padT);

  // KmatT[(c,d)][h] = l1[c][h] * W1c[h][d]
  kmat_k<<<dim3(4, 16384), 256, 0, stream>>>(lab, W1cT, KmatT);

  // merged: [tok | UV] = we @ [Wt | Wsp1^T-cat]  (N = 4096)
  gemm_k<1><<<dim3(32, 16), 256, 16384, stream>>>(we_b, WtT, 4096, 1024, UV, t0b, t1b,
                                                  bt, nullptr, nullptr, nullptr);
  // Avec = t0 @ W1a  (2048 x 512 f32)
  gemm_k<0><<<dim3(4, 16), 256, 16384, stream>>>(t0b, W1aT, 512, 1024, Avec, nullptr,
                                                 nullptr, nullptr, nullptr, nullptr, nullptr);
  // h = relu(t1@Kmat + Avec + BvecB); scores partials via MFMA W2 reduce
  gemm_k<2><<<dim3(128, 16), 256, 32768, stream>>>(t1b, KmatT, 16384, 1024, sPart, nullptr,
                                                   nullptr, nullptr, Avec, BvecB, W2padT);
  foldscores_k<<<768, 256, 0, stream>>>(sPart, b2, outS);
  mask_k<<<8, 256, 0, stream>>>(outS, is_s, is_e);

  // R = relu(U[s]+V[e]+bsp1) bf16; span idx/mask outputs
  rbuild_k<<<2048, 256, 0, stream>>>(UV, bsp1, is_s, is_e, R, outIdx, outMask);
  // span_logits = R @ MmT^T + cv
  spanout_k<<<192, 256, 0, stream>>>(R, MmTb, cv, outLog);
}